// Round 14
// baseline (601.389 us; speedup 1.0000x reference)
//
#include <hip/hip_runtime.h>
#include <hip/hip_bf16.h>

#define N_NODES 100000
#define E_EDGES 1600000
#define FDIM 128
#define NGRAPH 256
#define NPB 256            // nodes per bucket (dst >> 8)
#define NBUCKET 391        // ceil(N / 256)
#define SLAB 4800          // slab capacity (mean 4092, sigma ~64, +11 sigma)
#define BCHUNK 2048        // edges per bin block (small => parallelism)
#define NBINBLK ((E_EDGES + BCHUNK - 1) / BCHUNK)   // 782
#define LDSW 136           // padded bf16 row stride (128 + 8)
#define SREP 16            // stats replication

typedef __attribute__((ext_vector_type(8))) short bf16x8;
typedef __attribute__((ext_vector_type(4))) float f32x4;

__device__ __forceinline__ unsigned pack_bf16(float a, float b) {
    unsigned ua = __float_as_uint(a);
    unsigned ub = __float_as_uint(b);
    ua = ua + 0x7fffu + ((ua >> 16) & 1u);
    ub = ub + 0x7fffu + ((ub >> 16) & 1u);
    return (ua >> 16) | (ub & 0xffff0000u);
}
__device__ __forceinline__ unsigned short bf16_1(float a) {
    unsigned ua = __float_as_uint(a);
    ua = ua + 0x7fffu + ((ua >> 16) & 1u);
    return (unsigned short)(ua >> 16);
}
__device__ __forceinline__ float bf_lo(unsigned u) { return __uint_as_float(u << 16); }
__device__ __forceinline__ float bf_hi(unsigned u) { return __uint_as_float(u & 0xffff0000u); }

// ---------------- setup: stats/sums/cursor init + W^T bf16 precompute ---------

__global__ __launch_bounds__(256) void setupk(float* __restrict__ statsP,
                                              float* __restrict__ sums,
                                              int* __restrict__ cursor,
                                              const float* __restrict__ W1,
                                              const float* __restrict__ W2,
                                              const float* __restrict__ W3,
                                              unsigned short* __restrict__ Wt) {
    if (blockIdx.x < 128) {
        int i = blockIdx.x * 256 + threadIdx.x;
        if (i < 3 * SREP * 256) statsP[i] = 0.0f;
        if (i < NGRAPH * FDIM) sums[i] = 0.0f;
        if (i < NBUCKET) cursor[i] = i * SLAB;
    } else {
        int b = blockIdx.x - 128;
        int widx = b >> 3;
        int n0 = (b & 7) * 16;
        const float* W = (widx == 0) ? W1 : (widx == 1) ? W2 : W3;
        unsigned short* dst = Wt + widx * 16384;
        int t = threadIdx.x;
        int n = n0 + (t & 15);
#pragma unroll
        for (int i = 0; i < 8; i++) {
            int k = (t >> 4) + i * 16;
            dst[n * 128 + k] = bf16_1(W[k * 128 + n]);
        }
    }
}

// Phase 1: bin edges by dst bucket; clustered slab writes.
__global__ __launch_bounds__(256) void bink(const int* __restrict__ ei,
                                            int* __restrict__ cursor,
                                            int* __restrict__ bcsr) {
    __shared__ int hist[NBUCKET];
    __shared__ int base[NBUCKET];
    int t = threadIdx.x;
    for (int b = t; b < NBUCKET; b += 256) hist[b] = 0;
    __syncthreads();
    int e0 = blockIdx.x * BCHUNK;
    int e1 = e0 + BCHUNK; if (e1 > E_EDGES) e1 = E_EDGES;
    for (int e = e0 + t; e < e1; e += 256) {
        atomicAdd(&hist[ei[E_EDGES + e] >> 8], 1);
    }
    __syncthreads();
    for (int b = t; b < NBUCKET; b += 256) {
        int h = hist[b];
        base[b] = h ? atomicAdd(&cursor[b], h) : 0;
        hist[b] = 0;
    }
    __syncthreads();
    for (int e = e0 + t; e < e1; e += 256) {
        int s = ei[e];
        int d = ei[E_EDGES + e];
        int bk = d >> 8;
        int lp = atomicAdd(&hist[bk], 1);
        int pos = base[bk] + lp;
        if (pos < (bk + 1) * SLAB)                    // overflow guard
            bcsr[pos] = s | ((d & 255) << 17);
    }
}

// Phase 2: per-bucket LDS counting sort -> per-node grouping (in place, keeps
// dst-local bits), per-node offsets, in-counts, and dinv.
__global__ __launch_bounds__(256) void sortk(const int* __restrict__ cursor,
                                             int* __restrict__ bcsr,
                                             int* __restrict__ offs,
                                             int* __restrict__ inCnt,
                                             float* __restrict__ dinv) {
    __shared__ int ent[SLAB];      // 19.2 KB
    __shared__ int hist[NPB];
    __shared__ int hcur[NPB];
    __shared__ int htmp[NPB];
    int t = threadIdx.x;
    int bk = blockIdx.x;
    int slab = bk * SLAB;
    int cnt = cursor[bk] - slab;
    if (cnt > SLAB) cnt = SLAB;
    hist[t] = 0;
    __syncthreads();
    for (int i = t; i < cnt; i += 256) {
        int v = bcsr[slab + i];
        ent[i] = v;
        atomicAdd(&hist[v >> 17], 1);
    }
    __syncthreads();
    int myc = hist[t];
    htmp[t] = myc;
    __syncthreads();
    for (int st = 1; st < 256; st <<= 1) {
        int x = htmp[t];
        int y = (t >= st) ? htmp[t - st] : 0;
        __syncthreads();
        htmp[t] = x + y;
        __syncthreads();
    }
    int excl = htmp[t] - myc;
    hist[t] = excl;                 // reuse as scatter base
    hcur[t] = 0;
    int gn = bk * NPB + t;
    if (gn < N_NODES) {
        inCnt[gn] = myc;
        offs[gn] = slab + excl;
        dinv[gn] = rsqrtf((float)(1 + myc));   // +1 self-loop
    }
    __syncthreads();
    for (int i = t; i < cnt; i += 256) {
        int v = ent[i];
        int dl = v >> 17;
        int lp = atomicAdd(&hcur[dl], 1);
        bcsr[slab + hist[dl] + lp] = v;        // keep dl bits for coefk
    }
}

// Phase 3: expand to (src, coef) int2 entries; sequential, dinv L2-resident.
__global__ __launch_bounds__(256) void coefk(const int* __restrict__ cursor,
                                             const int* __restrict__ bcsr,
                                             const float* __restrict__ dinv,
                                             int2* __restrict__ csr2) {
    int bk = blockIdx.x;
    int slab = bk * SLAB;
    int cnt = cursor[bk] - slab;
    if (cnt > SLAB) cnt = SLAB;
    for (int i = threadIdx.x; i < cnt; i += 256) {
        int v = bcsr[slab + i];
        int s = v & 0x1FFFF;
        int d = bk * NPB + (v >> 17);
        csr2[slab + i] = make_int2(s, __float_as_int(dinv[s] * dinv[d]));
    }
}

// ---------------- MFMA GEMM: T_bf16[N,128] = act(A[N,128]) @ W ----------------
// MODE 0: A fp32, no BN (layer 1). MODE 1: A bf16 (uint-packed), BN+ReLU fused.

template <int MODE>
__global__ __launch_bounds__(256, 2) void gemmMF(const void* __restrict__ Ain,
                                                 const unsigned short* __restrict__ Wt,
                                                 const float* __restrict__ statsP,
                                                 const float* __restrict__ g,
                                                 const float* __restrict__ be,
                                                 unsigned short* __restrict__ outT) {
    __shared__ unsigned short sA[64 * LDSW];
    __shared__ unsigned short sW[128 * LDSW];
    __shared__ float sScale[FDIM], sBias[FDIM];
    int tid = threadIdx.x;
    if (MODE == 1) {
        if (tid < FDIM) {
            float s = 0.f, q = 0.f;
#pragma unroll
            for (int r = 0; r < SREP; r++) {
                s += statsP[r * 256 + tid];
                q += statsP[r * 256 + 128 + tid];
            }
            float mean = s * (1.0f / N_NODES);
            float var = q * (1.0f / N_NODES) - mean * mean;
            float sc = g[tid] * rsqrtf(var + 1e-5f);
            sScale[tid] = sc;
            sBias[tid] = be[tid] - mean * sc;
        }
        __syncthreads();
    }
    int row0 = blockIdx.x * 64;
    {
        const uint4* Wt4 = (const uint4*)Wt;
#pragma unroll
        for (int i = 0; i < 8; i++) {
            int flat = tid + 256 * i;        // 0..2047
            int r = flat >> 4, c8 = flat & 15;
            uint4 v = Wt4[flat];
            *(uint4*)&sW[r * LDSW + c8 * 8] = v;
        }
    }
    if (MODE == 0) {
        const float4* A4 = (const float4*)Ain;
#pragma unroll
        for (int i = 0; i < 8; i++) {
            int flat = tid + 256 * i;        // 0..2047
            int r = flat >> 5, c4 = flat & 31;
            int grow = row0 + r;
            float4 v = make_float4(0.f, 0.f, 0.f, 0.f);
            if (grow < N_NODES) v = A4[grow * 32 + c4];
            uint2 p;
            p.x = pack_bf16(v.x, v.y);
            p.y = pack_bf16(v.z, v.w);
            *(uint2*)&sA[r * LDSW + c4 * 4] = p;
        }
    } else {
        const uint2* A2 = (const uint2*)Ain;
#pragma unroll
        for (int i = 0; i < 8; i++) {
            int flat = tid + 256 * i;        // 0..2047
            int r = flat >> 5, c4 = flat & 31;
            int grow = row0 + r;
            uint2 u = make_uint2(0u, 0u);
            if (grow < N_NODES) u = A2[grow * 32 + c4];
            int ch = c4 * 4;
            float vx = fmaxf(bf_lo(u.x) * sScale[ch + 0] + sBias[ch + 0], 0.f);
            float vy = fmaxf(bf_hi(u.x) * sScale[ch + 1] + sBias[ch + 1], 0.f);
            float vz = fmaxf(bf_lo(u.y) * sScale[ch + 2] + sBias[ch + 2], 0.f);
            float vw = fmaxf(bf_hi(u.y) * sScale[ch + 3] + sBias[ch + 3], 0.f);
            uint2 p;
            p.x = pack_bf16(vx, vy);
            p.y = pack_bf16(vz, vw);
            *(uint2*)&sA[r * LDSW + c4 * 4] = p;
        }
    }
    __syncthreads();

    int lane = tid & 63;
    int w = tid >> 6;         // wave id: cols w*32..w*32+31
    int rbase = lane & 15;
    int kgrp = lane >> 4;     // 0..3
    f32x4 acc[4][2];
#pragma unroll
    for (int mf = 0; mf < 4; mf++)
#pragma unroll
        for (int nf = 0; nf < 2; nf++) acc[mf][nf] = (f32x4){0.f, 0.f, 0.f, 0.f};

#pragma unroll
    for (int kk = 0; kk < 4; kk++) {
        int kb = kk * 32 + kgrp * 8;
        bf16x8 af[4], bfr[2];
#pragma unroll
        for (int mf = 0; mf < 4; mf++)
            af[mf] = *(const bf16x8*)&sA[(mf * 16 + rbase) * LDSW + kb];
#pragma unroll
        for (int nf = 0; nf < 2; nf++)
            bfr[nf] = *(const bf16x8*)&sW[(w * 32 + nf * 16 + rbase) * LDSW + kb];
#pragma unroll
        for (int mf = 0; mf < 4; mf++)
#pragma unroll
            for (int nf = 0; nf < 2; nf++)
                acc[mf][nf] = __builtin_amdgcn_mfma_f32_16x16x32_bf16(
                    af[mf], bfr[nf], acc[mf][nf], 0, 0, 0);
    }
#pragma unroll
    for (int mf = 0; mf < 4; mf++) {
#pragma unroll
        for (int nf = 0; nf < 2; nf++) {
            int col = w * 32 + nf * 16 + rbase;
#pragma unroll
            for (int j = 0; j < 4; j++) {
                int grow = row0 + mf * 16 + kgrp * 4 + j;
                if (grow < N_NODES) {
                    outT[(size_t)grow * FDIM + col] = bf16_1(acc[mf][nf][j]);
                }
            }
        }
    }
}

// ---------------- edge aggregation (pair-gather) + fused BN stats -------------
// 3125 blocks x 4 waves x 8 nodes. Halves of the wave cover edges e and e+1
// with uint2 (8B) row segments: ONE VMEM instruction serves 2 edges. CSR entry
// reads stay wave-uniform scalar; per-half select via cndmask.
// lane: half = lane>>5, sub = lane&31 (channels 4sub..4sub+3).

__global__ __launch_bounds__(256) void agg(const uint2* __restrict__ t2,
                                           const int2* __restrict__ csr2,
                                           const int* __restrict__ offs,
                                           const int* __restrict__ inCnt,
                                           const float* __restrict__ dinv,
                                           const float* __restrict__ bias,
                                           uint2* __restrict__ outH2,
                                           float* __restrict__ statsP) {
    int tid = threadIdx.x;
    int lane = tid & 63;
    int half = lane >> 5;
    int sub = lane & 31;
    int wid = tid >> 6;
    float4 b4 = ((const float4*)bias)[sub];
    float s0 = 0.f, s1 = 0.f, s2 = 0.f, s3 = 0.f;
    float q0 = 0.f, q1 = 0.f, q2 = 0.f, q3 = 0.f;
    for (int it = 0; it < 8; it++) {
        int node = __builtin_amdgcn_readfirstlane(blockIdx.x * 32 + wid * 8 + it);
        float di = dinv[node];
        uint2 su = t2[node * 32 + sub];
        float cs = half ? 0.f : di * di;        // self-loop on half 0 only
        float a0 = cs * bf_lo(su.x), a1 = cs * bf_hi(su.x);
        float a2 = cs * bf_lo(su.y), a3 = cs * bf_hi(su.y);
        int start = offs[node];
        int cnt = inCnt[node];
        int e = 0;
        for (; e + 16 <= cnt; e += 16) {
            int2 E[16];
#pragma unroll
            for (int k = 0; k < 16; k++) E[k] = csr2[start + e + k];   // scalar
            uint2 U[8];
#pragma unroll
            for (int p = 0; p < 8; p++) {
                int src = half ? E[2 * p + 1].x : E[2 * p].x;
                U[p] = t2[src * 32 + sub];
            }
#pragma unroll
            for (int p = 0; p < 8; p++) {
                float f = __int_as_float(half ? E[2 * p + 1].y : E[2 * p].y);
                a0 += f * bf_lo(U[p].x); a1 += f * bf_hi(U[p].x);
                a2 += f * bf_lo(U[p].y); a3 += f * bf_hi(U[p].y);
            }
        }
        for (; e + 2 <= cnt; e += 2) {
            int2 E0 = csr2[start + e];
            int2 E1 = csr2[start + e + 1];
            int src = half ? E1.x : E0.x;
            uint2 U = t2[src * 32 + sub];
            float f = __int_as_float(half ? E1.y : E0.y);
            a0 += f * bf_lo(U.x); a1 += f * bf_hi(U.x);
            a2 += f * bf_lo(U.y); a3 += f * bf_hi(U.y);
        }
        if (e < cnt) {                           // odd tail: half 1 masked
            int2 E = csr2[start + e];
            uint2 U = t2[E.x * 32 + sub];
            float f = half ? 0.f : __int_as_float(E.y);
            a0 += f * bf_lo(U.x); a1 += f * bf_hi(U.x);
            a2 += f * bf_lo(U.y); a3 += f * bf_hi(U.y);
        }
        // fold the two halves
        a0 += __shfl_xor(a0, 32, 64);
        a1 += __shfl_xor(a1, 32, 64);
        a2 += __shfl_xor(a2, 32, 64);
        a3 += __shfl_xor(a3, 32, 64);
        a0 += b4.x; a1 += b4.y; a2 += b4.z; a3 += b4.w;
        if (half == 0) {
            uint2 p;
            p.x = pack_bf16(a0, a1);
            p.y = pack_bf16(a2, a3);
            outH2[node * 32 + sub] = p;
            s0 += a0; q0 += a0 * a0;
            s1 += a1; q1 += a1 * a1;
            s2 += a2; q2 += a2 * a2;
            s3 += a3; q3 += a3 * a3;
        }
    }
    // stats: per-wave 128-channel partials, cross-wave reduce, one atomic flush
    __shared__ float sS[4][128], sQ[4][128];
    if (half == 0) {
        sS[wid][4 * sub + 0] = s0; sQ[wid][4 * sub + 0] = q0;
        sS[wid][4 * sub + 1] = s1; sQ[wid][4 * sub + 1] = q1;
        sS[wid][4 * sub + 2] = s2; sQ[wid][4 * sub + 2] = q2;
        sS[wid][4 * sub + 3] = s3; sQ[wid][4 * sub + 3] = q3;
    }
    __syncthreads();
    if (tid < 128) {
        float S = sS[0][tid] + sS[1][tid] + sS[2][tid] + sS[3][tid];
        float Q = sQ[0][tid] + sQ[1][tid] + sQ[2][tid] + sQ[3][tid];
        float* p = statsP + (blockIdx.x & (SREP - 1)) * 256;
        atomicAdd(&p[tid], S);
        atomicAdd(&p[128 + tid], Q);
    }
}

// ---------------- pool phase 1: BN3+ReLU + segment-sum (bf16 H) ----------------

__global__ __launch_bounds__(128) void poolsum(const unsigned* __restrict__ h,
                                               const int* __restrict__ batch,
                                               const float* __restrict__ statsP,
                                               const float* __restrict__ g3,
                                               const float* __restrict__ be3,
                                               float* __restrict__ sums) {
    int c = threadIdx.x;
    int base = blockIdx.x * 64;
    float s = 0.f, q = 0.f;
#pragma unroll
    for (int r = 0; r < SREP; r++) {
        s += statsP[r * 256 + c];
        q += statsP[r * 256 + 128 + c];
    }
    float mean = s * (1.0f / N_NODES);
    float var = q * (1.0f / N_NODES) - mean * mean;
    float sc = g3[c] * rsqrtf(var + 1e-5f);
    float bi = be3[c] - mean * sc;
    __shared__ int sb[64];
    if (c < 64) {
        int idx = base + c;
        sb[c] = (idx < N_NODES) ? batch[idx] : -1;
    }
    __syncthreads();
    float acc = 0.f;
    int gcur = sb[0];
    int half = c & 1;
    int cu = c >> 1;
    for (int r = 0; r < 64; r++) {
        int idx = base + r;
        if (idx >= N_NODES) break;
        int gr = sb[r];
        if (gr != gcur) {
            atomicAdd(&sums[gcur * FDIM + c], acc);
            acc = 0.f;
            gcur = gr;
        }
        unsigned u = h[(size_t)idx * 64 + cu];
        float v = half ? bf_hi(u) : bf_lo(u);
        acc += fmaxf(v * sc + bi, 0.f);
    }
    atomicAdd(&sums[gcur * FDIM + c], acc);
}

// ---------------- pool phase 2: divide + final linear ----------------

__global__ __launch_bounds__(128) void finalk(const float* __restrict__ sums,
                                              const int* __restrict__ batch,
                                              const float* __restrict__ Wl,
                                              const float* __restrict__ bl,
                                              float* __restrict__ out) {
    int g = blockIdx.x;
    int c = threadIdx.x;
    int lo = 0, hi = N_NODES;
    while (lo < hi) { int m = (lo + hi) >> 1; if (batch[m] < g) lo = m + 1; else hi = m; }
    int start = lo;
    lo = start; hi = N_NODES;
    while (lo < hi) { int m = (lo + hi) >> 1; if (batch[m] < g + 1) lo = m + 1; else hi = m; }
    int cnt = lo - start;
    float v = sums[g * FDIM + c] / fmaxf((float)cnt, 1.0f) * Wl[c];
    __shared__ float red[FDIM];
    red[c] = v;
    __syncthreads();
    for (int st = 64; st > 0; st >>= 1) {
        if (c < st) red[c] += red[c + st];
        __syncthreads();
    }
    if (c == 0) out[g] = red[0] + bl[0];
}

// ---------------- launch ----------------

extern "C" void kernel_launch(void* const* d_in, const int* in_sizes, int n_in,
                              void* d_out, int out_size, void* d_ws, size_t ws_size,
                              hipStream_t stream) {
    const float* x  = (const float*)d_in[0];
    const int* ei   = (const int*)d_in[1];
    const int* batch = (const int*)d_in[2];
    const float* W1 = (const float*)d_in[3];
    const float* b1 = (const float*)d_in[4];
    const float* g1 = (const float*)d_in[5];
    const float* be1 = (const float*)d_in[6];
    const float* W2 = (const float*)d_in[7];
    const float* b2 = (const float*)d_in[8];
    const float* g2 = (const float*)d_in[9];
    const float* be2 = (const float*)d_in[10];
    const float* W3 = (const float*)d_in[11];
    const float* b3 = (const float*)d_in[12];
    const float* g3 = (const float*)d_in[13];
    const float* be3 = (const float*)d_in[14];
    const float* Wl = (const float*)d_in[15];
    const float* bl = (const float*)d_in[16];
    float* out = (float*)d_out;

    char* ws = (char*)d_ws;
    size_t off = 0;
    auto alloc = [&](size_t bytes) -> char* {
        char* p = ws + off;
        off = (off + bytes + 255) & ~(size_t)255;
        return p;
    };
    float* dinv    = (float*)alloc(N_NODES * 4);
    int* offs      = (int*)alloc(N_NODES * 4);
    int* inCnt     = (int*)alloc(N_NODES * 4);
    int* cursor    = (int*)alloc(NBUCKET * 4);
    int* bcsr      = (int*)alloc((size_t)NBUCKET * SLAB * 4);
    int2* csr2     = (int2*)alloc((size_t)NBUCKET * SLAB * 8);
    float* statsP  = (float*)alloc(3 * SREP * 256 * 4);
    float* sums    = (float*)alloc(NGRAPH * FDIM * 4);
    unsigned short* Wt = (unsigned short*)alloc(3 * 16384 * 2);
    unsigned short* T16 = (unsigned short*)alloc((size_t)N_NODES * FDIM * 2);
    unsigned* H    = (unsigned*)alloc((size_t)N_NODES * 64 * 4);

    const int nb_gemm = (N_NODES + 63) / 64;      // 1563
    const int nb_agg = N_NODES / 32;              // 3125
    const int nb_pool = (N_NODES + 63) / 64;      // 1563

    // setup (init + W transpose) -> bin -> sort -> coef
    setupk<<<152, 256, 0, stream>>>(statsP, sums, cursor, W1, W2, W3, Wt);
    bink<<<NBINBLK, 256, 0, stream>>>(ei, cursor, bcsr);
    sortk<<<NBUCKET, 256, 0, stream>>>(cursor, bcsr, offs, inCnt, dinv);
    coefk<<<NBUCKET, 256, 0, stream>>>(cursor, bcsr, dinv, csr2);

    // layer 1
    gemmMF<0><<<nb_gemm, 256, 0, stream>>>(x, Wt, nullptr, nullptr, nullptr, T16);
    agg<<<nb_agg, 256, 0, stream>>>((const uint2*)T16, csr2, offs, inCnt, dinv, b1,
                                    (uint2*)H, statsP);

    // layer 2 (BN1+ReLU fused into GEMM A-stage)
    gemmMF<1><<<nb_gemm, 256, 0, stream>>>(H, Wt + 16384, statsP, g1, be1, T16);
    agg<<<nb_agg, 256, 0, stream>>>((const uint2*)T16, csr2, offs, inCnt, dinv, b2,
                                    (uint2*)H, statsP + SREP * 256);

    // layer 3
    gemmMF<1><<<nb_gemm, 256, 0, stream>>>(H, Wt + 32768, statsP + SREP * 256, g2, be2, T16);
    agg<<<nb_agg, 256, 0, stream>>>((const uint2*)T16, csr2, offs, inCnt, dinv, b3,
                                    (uint2*)H, statsP + 2 * SREP * 256);

    // pool (BN3+ReLU fused) + linear
    poolsum<<<nb_pool, 128, 0, stream>>>(H, batch, statsP + 2 * SREP * 256, g3, be3, sums);
    finalk<<<NGRAPH, 128, 0, stream>>>(sums, batch, Wl, bl, out);
}

// Round 15
// 357.906 us; speedup vs baseline: 1.6803x; 1.6803x over previous
//
#include <hip/hip_runtime.h>
#include <hip/hip_bf16.h>

#define N_NODES 100000
#define E_EDGES 1600000
#define FDIM 128
#define NGRAPH 256
#define NPB 256            // nodes per bucket (dst >> 8)
#define NBUCKET 391        // ceil(N / 256)
#define SLAB 4800          // slab capacity (mean 4092, sigma ~64, +11 sigma)
#define BCHUNK 2048        // edges per bin block (small => parallelism)
#define NBINBLK ((E_EDGES + BCHUNK - 1) / BCHUNK)   // 782
#define LDSW 136           // padded bf16 row stride (128 + 8)
#define SREP 16            // stats replication

typedef __attribute__((ext_vector_type(8))) short bf16x8;
typedef __attribute__((ext_vector_type(4))) float f32x4;

__device__ __forceinline__ unsigned pack_bf16(float a, float b) {
    unsigned ua = __float_as_uint(a);
    unsigned ub = __float_as_uint(b);
    ua = ua + 0x7fffu + ((ua >> 16) & 1u);
    ub = ub + 0x7fffu + ((ub >> 16) & 1u);
    return (ua >> 16) | (ub & 0xffff0000u);
}
__device__ __forceinline__ unsigned short bf16_1(float a) {
    unsigned ua = __float_as_uint(a);
    ua = ua + 0x7fffu + ((ua >> 16) & 1u);
    return (unsigned short)(ua >> 16);
}
__device__ __forceinline__ float bf_lo(unsigned u) { return __uint_as_float(u << 16); }
__device__ __forceinline__ float bf_hi(unsigned u) { return __uint_as_float(u & 0xffff0000u); }

// ---------------- setup: stats/sums/cursor init + W^T bf16 precompute ---------

__global__ __launch_bounds__(256) void setupk(float* __restrict__ statsP,
                                              float* __restrict__ sums,
                                              int* __restrict__ cursor,
                                              const float* __restrict__ W1,
                                              const float* __restrict__ W2,
                                              const float* __restrict__ W3,
                                              unsigned short* __restrict__ Wt) {
    if (blockIdx.x < 128) {
        int i = blockIdx.x * 256 + threadIdx.x;
        if (i < 3 * SREP * 256) statsP[i] = 0.0f;
        if (i < NGRAPH * FDIM) sums[i] = 0.0f;
        if (i < NBUCKET) cursor[i] = i * SLAB;
    } else {
        int b = blockIdx.x - 128;
        int widx = b >> 3;
        int n0 = (b & 7) * 16;
        const float* W = (widx == 0) ? W1 : (widx == 1) ? W2 : W3;
        unsigned short* dst = Wt + widx * 16384;
        int t = threadIdx.x;
        int n = n0 + (t & 15);
#pragma unroll
        for (int i = 0; i < 8; i++) {
            int k = (t >> 4) + i * 16;
            dst[n * 128 + k] = bf16_1(W[k * 128 + n]);
        }
    }
}

// Phase 1: bin edges by dst bucket; clustered slab writes.
__global__ __launch_bounds__(256) void bink(const int* __restrict__ ei,
                                            int* __restrict__ cursor,
                                            int* __restrict__ bcsr) {
    __shared__ int hist[NBUCKET];
    __shared__ int base[NBUCKET];
    int t = threadIdx.x;
    for (int b = t; b < NBUCKET; b += 256) hist[b] = 0;
    __syncthreads();
    int e0 = blockIdx.x * BCHUNK;
    int e1 = e0 + BCHUNK; if (e1 > E_EDGES) e1 = E_EDGES;
    for (int e = e0 + t; e < e1; e += 256) {
        atomicAdd(&hist[ei[E_EDGES + e] >> 8], 1);
    }
    __syncthreads();
    for (int b = t; b < NBUCKET; b += 256) {
        int h = hist[b];
        base[b] = h ? atomicAdd(&cursor[b], h) : 0;
        hist[b] = 0;
    }
    __syncthreads();
    for (int e = e0 + t; e < e1; e += 256) {
        int s = ei[e];
        int d = ei[E_EDGES + e];
        int bk = d >> 8;
        int lp = atomicAdd(&hist[bk], 1);
        int pos = base[bk] + lp;
        if (pos < (bk + 1) * SLAB)                    // overflow guard
            bcsr[pos] = s | ((d & 255) << 17);
    }
}

// Phase 2: per-bucket LDS counting sort -> per-node grouping (in place, keeps
// dst-local bits), per-node offsets, in-counts, and dinv.
__global__ __launch_bounds__(256) void sortk(const int* __restrict__ cursor,
                                             int* __restrict__ bcsr,
                                             int* __restrict__ offs,
                                             int* __restrict__ inCnt,
                                             float* __restrict__ dinv) {
    __shared__ int ent[SLAB];      // 19.2 KB
    __shared__ int hist[NPB];
    __shared__ int hcur[NPB];
    __shared__ int htmp[NPB];
    int t = threadIdx.x;
    int bk = blockIdx.x;
    int slab = bk * SLAB;
    int cnt = cursor[bk] - slab;
    if (cnt > SLAB) cnt = SLAB;
    hist[t] = 0;
    __syncthreads();
    for (int i = t; i < cnt; i += 256) {
        int v = bcsr[slab + i];
        ent[i] = v;
        atomicAdd(&hist[v >> 17], 1);
    }
    __syncthreads();
    int myc = hist[t];
    htmp[t] = myc;
    __syncthreads();
    for (int st = 1; st < 256; st <<= 1) {
        int x = htmp[t];
        int y = (t >= st) ? htmp[t - st] : 0;
        __syncthreads();
        htmp[t] = x + y;
        __syncthreads();
    }
    int excl = htmp[t] - myc;
    hist[t] = excl;                 // reuse as scatter base
    hcur[t] = 0;
    int gn = bk * NPB + t;
    if (gn < N_NODES) {
        inCnt[gn] = myc;
        offs[gn] = slab + excl;
        dinv[gn] = rsqrtf((float)(1 + myc));   // +1 self-loop
    }
    __syncthreads();
    for (int i = t; i < cnt; i += 256) {
        int v = ent[i];
        int dl = v >> 17;
        int lp = atomicAdd(&hcur[dl], 1);
        bcsr[slab + hist[dl] + lp] = v;        // keep dl bits for coefk
    }
}

// Phase 3: expand to (src, coef) int2 entries; sequential, dinv L2-resident.
__global__ __launch_bounds__(256) void coefk(const int* __restrict__ cursor,
                                             const int* __restrict__ bcsr,
                                             const float* __restrict__ dinv,
                                             int2* __restrict__ csr2) {
    int bk = blockIdx.x;
    int slab = bk * SLAB;
    int cnt = cursor[bk] - slab;
    if (cnt > SLAB) cnt = SLAB;
    for (int i = threadIdx.x; i < cnt; i += 256) {
        int v = bcsr[slab + i];
        int s = v & 0x1FFFF;
        int d = bk * NPB + (v >> 17);
        csr2[slab + i] = make_int2(s, __float_as_int(dinv[s] * dinv[d]));
    }
}

// ---------------- MFMA GEMM: T_bf16[N,128] = act(A[N,128]) @ W ----------------
// MODE 0: A fp32, no BN (layer 1). MODE 1: A bf16 (uint-packed), BN+ReLU fused.

template <int MODE>
__global__ __launch_bounds__(256, 3) void gemmMF(const void* __restrict__ Ain,
                                                 const unsigned short* __restrict__ Wt,
                                                 const float* __restrict__ statsP,
                                                 const float* __restrict__ g,
                                                 const float* __restrict__ be,
                                                 unsigned short* __restrict__ outT) {
    __shared__ unsigned short sA[64 * LDSW];
    __shared__ unsigned short sW[128 * LDSW];
    __shared__ float sScale[FDIM], sBias[FDIM];
    int tid = threadIdx.x;
    if (MODE == 1) {
        if (tid < FDIM) {
            float s = 0.f, q = 0.f;
#pragma unroll
            for (int r = 0; r < SREP; r++) {
                s += statsP[r * 256 + tid];
                q += statsP[r * 256 + 128 + tid];
            }
            float mean = s * (1.0f / N_NODES);
            float var = q * (1.0f / N_NODES) - mean * mean;
            float sc = g[tid] * rsqrtf(var + 1e-5f);
            sScale[tid] = sc;
            sBias[tid] = be[tid] - mean * sc;
        }
        __syncthreads();
    }
    int row0 = blockIdx.x * 64;
    {
        const uint4* Wt4 = (const uint4*)Wt;
#pragma unroll
        for (int i = 0; i < 8; i++) {
            int flat = tid + 256 * i;        // 0..2047
            int r = flat >> 4, c8 = flat & 15;
            uint4 v = Wt4[flat];
            *(uint4*)&sW[r * LDSW + c8 * 8] = v;
        }
    }
    if (MODE == 0) {
        const float4* A4 = (const float4*)Ain;
#pragma unroll
        for (int i = 0; i < 8; i++) {
            int flat = tid + 256 * i;        // 0..2047
            int r = flat >> 5, c4 = flat & 31;
            int grow = row0 + r;
            float4 v = make_float4(0.f, 0.f, 0.f, 0.f);
            if (grow < N_NODES) v = A4[grow * 32 + c4];
            uint2 p;
            p.x = pack_bf16(v.x, v.y);
            p.y = pack_bf16(v.z, v.w);
            *(uint2*)&sA[r * LDSW + c4 * 4] = p;
        }
    } else {
        const uint2* A2 = (const uint2*)Ain;
#pragma unroll
        for (int i = 0; i < 8; i++) {
            int flat = tid + 256 * i;        // 0..2047
            int r = flat >> 5, c4 = flat & 31;
            int grow = row0 + r;
            uint2 u = make_uint2(0u, 0u);
            if (grow < N_NODES) u = A2[grow * 32 + c4];
            int ch = c4 * 4;
            float vx = fmaxf(bf_lo(u.x) * sScale[ch + 0] + sBias[ch + 0], 0.f);
            float vy = fmaxf(bf_hi(u.x) * sScale[ch + 1] + sBias[ch + 1], 0.f);
            float vz = fmaxf(bf_lo(u.y) * sScale[ch + 2] + sBias[ch + 2], 0.f);
            float vw = fmaxf(bf_hi(u.y) * sScale[ch + 3] + sBias[ch + 3], 0.f);
            uint2 p;
            p.x = pack_bf16(vx, vy);
            p.y = pack_bf16(vz, vw);
            *(uint2*)&sA[r * LDSW + c4 * 4] = p;
        }
    }
    __syncthreads();

    int lane = tid & 63;
    int w = tid >> 6;         // wave id: cols w*32..w*32+31
    int rbase = lane & 15;
    int kgrp = lane >> 4;     // 0..3
    f32x4 acc[4][2];
#pragma unroll
    for (int mf = 0; mf < 4; mf++)
#pragma unroll
        for (int nf = 0; nf < 2; nf++) acc[mf][nf] = (f32x4){0.f, 0.f, 0.f, 0.f};

#pragma unroll
    for (int kk = 0; kk < 4; kk++) {
        int kb = kk * 32 + kgrp * 8;
        bf16x8 af[4], bfr[2];
#pragma unroll
        for (int mf = 0; mf < 4; mf++)
            af[mf] = *(const bf16x8*)&sA[(mf * 16 + rbase) * LDSW + kb];
#pragma unroll
        for (int nf = 0; nf < 2; nf++)
            bfr[nf] = *(const bf16x8*)&sW[(w * 32 + nf * 16 + rbase) * LDSW + kb];
#pragma unroll
        for (int mf = 0; mf < 4; mf++)
#pragma unroll
            for (int nf = 0; nf < 2; nf++)
                acc[mf][nf] = __builtin_amdgcn_mfma_f32_16x16x32_bf16(
                    af[mf], bfr[nf], acc[mf][nf], 0, 0, 0);
    }
#pragma unroll
    for (int mf = 0; mf < 4; mf++) {
#pragma unroll
        for (int nf = 0; nf < 2; nf++) {
            int col = w * 32 + nf * 16 + rbase;
#pragma unroll
            for (int j = 0; j < 4; j++) {
                int grow = row0 + mf * 16 + kgrp * 4 + j;
                if (grow < N_NODES) {
                    outT[(size_t)grow * FDIM + col] = bf16_1(acc[mf][nf][j]);
                }
            }
        }
    }
}

// ---------------- edge aggregation (gather form, unroll-8) + fused BN stats ----
// 3125 blocks x 4 waves x 8 nodes; lane = channel-pair; bf16 in/out.
// CSR entry reads are wave-uniform -> scalar loads (keep them that way).

__global__ __launch_bounds__(256) void agg(const unsigned* __restrict__ t,
                                           const int2* __restrict__ csr2,
                                           const int* __restrict__ offs,
                                           const int* __restrict__ inCnt,
                                           const float* __restrict__ dinv,
                                           const float* __restrict__ bias,
                                           unsigned* __restrict__ outH,
                                           float* __restrict__ statsP) {
    int tid = threadIdx.x;
    int lane = tid & 63;
    int wid = tid >> 6;
    const float2* bias2 = (const float2*)bias;
    float2 b = bias2[lane];
    float s0 = 0.f, s1 = 0.f, q0 = 0.f, q1 = 0.f;
    for (int it = 0; it < 8; it++) {
        int node = __builtin_amdgcn_readfirstlane(blockIdx.x * 32 + wid * 8 + it);
        float di = dinv[node];
        unsigned su = t[node * 64 + lane];
        float cs = di * di;
        float a0 = bf_lo(su) * cs;
        float a1 = bf_hi(su) * cs;
        int start = offs[node];
        int cnt = inCnt[node];
        int e = 0;
        for (; e + 8 <= cnt; e += 8) {
            int2 E0 = csr2[start + e + 0];
            int2 E1 = csr2[start + e + 1];
            int2 E2 = csr2[start + e + 2];
            int2 E3 = csr2[start + e + 3];
            int2 E4 = csr2[start + e + 4];
            int2 E5 = csr2[start + e + 5];
            int2 E6 = csr2[start + e + 6];
            int2 E7 = csr2[start + e + 7];
            unsigned u0 = t[E0.x * 64 + lane];
            unsigned u1 = t[E1.x * 64 + lane];
            unsigned u2 = t[E2.x * 64 + lane];
            unsigned u3 = t[E3.x * 64 + lane];
            unsigned u4 = t[E4.x * 64 + lane];
            unsigned u5 = t[E5.x * 64 + lane];
            unsigned u6 = t[E6.x * 64 + lane];
            unsigned u7 = t[E7.x * 64 + lane];
            float f0 = __int_as_float(E0.y);
            float f1 = __int_as_float(E1.y);
            float f2 = __int_as_float(E2.y);
            float f3 = __int_as_float(E3.y);
            float f4 = __int_as_float(E4.y);
            float f5 = __int_as_float(E5.y);
            float f6 = __int_as_float(E6.y);
            float f7 = __int_as_float(E7.y);
            a0 += f0 * bf_lo(u0); a1 += f0 * bf_hi(u0);
            a0 += f1 * bf_lo(u1); a1 += f1 * bf_hi(u1);
            a0 += f2 * bf_lo(u2); a1 += f2 * bf_hi(u2);
            a0 += f3 * bf_lo(u3); a1 += f3 * bf_hi(u3);
            a0 += f4 * bf_lo(u4); a1 += f4 * bf_hi(u4);
            a0 += f5 * bf_lo(u5); a1 += f5 * bf_hi(u5);
            a0 += f6 * bf_lo(u6); a1 += f6 * bf_hi(u6);
            a0 += f7 * bf_lo(u7); a1 += f7 * bf_hi(u7);
        }
        for (; e + 4 <= cnt; e += 4) {
            int2 E0 = csr2[start + e + 0];
            int2 E1 = csr2[start + e + 1];
            int2 E2 = csr2[start + e + 2];
            int2 E3 = csr2[start + e + 3];
            unsigned u0 = t[E0.x * 64 + lane];
            unsigned u1 = t[E1.x * 64 + lane];
            unsigned u2 = t[E2.x * 64 + lane];
            unsigned u3 = t[E3.x * 64 + lane];
            float f0 = __int_as_float(E0.y);
            float f1 = __int_as_float(E1.y);
            float f2 = __int_as_float(E2.y);
            float f3 = __int_as_float(E3.y);
            a0 += f0 * bf_lo(u0); a1 += f0 * bf_hi(u0);
            a0 += f1 * bf_lo(u1); a1 += f1 * bf_hi(u1);
            a0 += f2 * bf_lo(u2); a1 += f2 * bf_hi(u2);
            a0 += f3 * bf_lo(u3); a1 += f3 * bf_hi(u3);
        }
        for (; e < cnt; e++) {
            int2 E = csr2[start + e];
            float cf = __int_as_float(E.y);
            unsigned u = t[E.x * 64 + lane];
            a0 += cf * bf_lo(u);
            a1 += cf * bf_hi(u);
        }
        a0 += b.x;
        a1 += b.y;
        outH[node * 64 + lane] = pack_bf16(a0, a1);
        s0 += a0; q0 += a0 * a0;
        s1 += a1; q1 += a1 * a1;
    }
    __shared__ float rS0[256], rS1[256], rQ0[256], rQ1[256];
    rS0[tid] = s0; rS1[tid] = s1; rQ0[tid] = q0; rQ1[tid] = q1;
    __syncthreads();
    if (tid < 64) {
        float S0 = 0.f, S1 = 0.f, Q0 = 0.f, Q1 = 0.f;
#pragma unroll
        for (int w = 0; w < 4; w++) {
            S0 += rS0[w * 64 + tid];
            S1 += rS1[w * 64 + tid];
            Q0 += rQ0[w * 64 + tid];
            Q1 += rQ1[w * 64 + tid];
        }
        float* p = statsP + (blockIdx.x & (SREP - 1)) * 256;
        atomicAdd(&p[2 * tid + 0], S0);
        atomicAdd(&p[2 * tid + 1], S1);
        atomicAdd(&p[128 + 2 * tid + 0], Q0);
        atomicAdd(&p[128 + 2 * tid + 1], Q1);
    }
}

// ---------------- pool phase 1: BN3+ReLU + segment-sum (bf16 H) ----------------

__global__ __launch_bounds__(128) void poolsum(const unsigned* __restrict__ h,
                                               const int* __restrict__ batch,
                                               const float* __restrict__ statsP,
                                               const float* __restrict__ g3,
                                               const float* __restrict__ be3,
                                               float* __restrict__ sums) {
    int c = threadIdx.x;
    int base = blockIdx.x * 64;
    float s = 0.f, q = 0.f;
#pragma unroll
    for (int r = 0; r < SREP; r++) {
        s += statsP[r * 256 + c];
        q += statsP[r * 256 + 128 + c];
    }
    float mean = s * (1.0f / N_NODES);
    float var = q * (1.0f / N_NODES) - mean * mean;
    float sc = g3[c] * rsqrtf(var + 1e-5f);
    float bi = be3[c] - mean * sc;
    __shared__ int sb[64];
    if (c < 64) {
        int idx = base + c;
        sb[c] = (idx < N_NODES) ? batch[idx] : -1;
    }
    __syncthreads();
    float acc = 0.f;
    int gcur = sb[0];
    int half = c & 1;
    int cu = c >> 1;
    for (int r = 0; r < 64; r++) {
        int idx = base + r;
        if (idx >= N_NODES) break;
        int gr = sb[r];
        if (gr != gcur) {
            atomicAdd(&sums[gcur * FDIM + c], acc);
            acc = 0.f;
            gcur = gr;
        }
        unsigned u = h[(size_t)idx * 64 + cu];
        float v = half ? bf_hi(u) : bf_lo(u);
        acc += fmaxf(v * sc + bi, 0.f);
    }
    atomicAdd(&sums[gcur * FDIM + c], acc);
}

// ---------------- pool phase 2: divide + final linear ----------------

__global__ __launch_bounds__(128) void finalk(const float* __restrict__ sums,
                                              const int* __restrict__ batch,
                                              const float* __restrict__ Wl,
                                              const float* __restrict__ bl,
                                              float* __restrict__ out) {
    int g = blockIdx.x;
    int c = threadIdx.x;
    int lo = 0, hi = N_NODES;
    while (lo < hi) { int m = (lo + hi) >> 1; if (batch[m] < g) lo = m + 1; else hi = m; }
    int start = lo;
    lo = start; hi = N_NODES;
    while (lo < hi) { int m = (lo + hi) >> 1; if (batch[m] < g + 1) lo = m + 1; else hi = m; }
    int cnt = lo - start;
    float v = sums[g * FDIM + c] / fmaxf((float)cnt, 1.0f) * Wl[c];
    __shared__ float red[FDIM];
    red[c] = v;
    __syncthreads();
    for (int st = 64; st > 0; st >>= 1) {
        if (c < st) red[c] += red[c + st];
        __syncthreads();
    }
    if (c == 0) out[g] = red[0] + bl[0];
}

// ---------------- launch ----------------

extern "C" void kernel_launch(void* const* d_in, const int* in_sizes, int n_in,
                              void* d_out, int out_size, void* d_ws, size_t ws_size,
                              hipStream_t stream) {
    const float* x  = (const float*)d_in[0];
    const int* ei   = (const int*)d_in[1];
    const int* batch = (const int*)d_in[2];
    const float* W1 = (const float*)d_in[3];
    const float* b1 = (const float*)d_in[4];
    const float* g1 = (const float*)d_in[5];
    const float* be1 = (const float*)d_in[6];
    const float* W2 = (const float*)d_in[7];
    const float* b2 = (const float*)d_in[8];
    const float* g2 = (const float*)d_in[9];
    const float* be2 = (const float*)d_in[10];
    const float* W3 = (const float*)d_in[11];
    const float* b3 = (const float*)d_in[12];
    const float* g3 = (const float*)d_in[13];
    const float* be3 = (const float*)d_in[14];
    const float* Wl = (const float*)d_in[15];
    const float* bl = (const float*)d_in[16];
    float* out = (float*)d_out;

    char* ws = (char*)d_ws;
    size_t off = 0;
    auto alloc = [&](size_t bytes) -> char* {
        char* p = ws + off;
        off = (off + bytes + 255) & ~(size_t)255;
        return p;
    };
    float* dinv    = (float*)alloc(N_NODES * 4);
    int* offs      = (int*)alloc(N_NODES * 4);
    int* inCnt     = (int*)alloc(N_NODES * 4);
    int* cursor    = (int*)alloc(NBUCKET * 4);
    int* bcsr      = (int*)alloc((size_t)NBUCKET * SLAB * 4);
    int2* csr2     = (int2*)alloc((size_t)NBUCKET * SLAB * 8);
    float* statsP  = (float*)alloc(3 * SREP * 256 * 4);
    float* sums    = (float*)alloc(NGRAPH * FDIM * 4);
    unsigned short* Wt = (unsigned short*)alloc(3 * 16384 * 2);
    unsigned short* T16 = (unsigned short*)alloc((size_t)N_NODES * FDIM * 2);
    unsigned* H    = (unsigned*)alloc((size_t)N_NODES * 64 * 4);

    const int nb_gemm = (N_NODES + 63) / 64;      // 1563
    const int nb_agg = N_NODES / 32;              // 3125
    const int nb_pool = (N_NODES + 63) / 64;      // 1563

    // setup (init + W transpose) -> bin -> sort -> coef
    setupk<<<152, 256, 0, stream>>>(statsP, sums, cursor, W1, W2, W3, Wt);
    bink<<<NBINBLK, 256, 0, stream>>>(ei, cursor, bcsr);
    sortk<<<NBUCKET, 256, 0, stream>>>(cursor, bcsr, offs, inCnt, dinv);
    coefk<<<NBUCKET, 256, 0, stream>>>(cursor, bcsr, dinv, csr2);

    // layer 1
    gemmMF<0><<<nb_gemm, 256, 0, stream>>>(x, Wt, nullptr, nullptr, nullptr, T16);
    agg<<<nb_agg, 256, 0, stream>>>((const unsigned*)T16, csr2, offs, inCnt, dinv, b1, H, statsP);

    // layer 2 (BN1+ReLU fused into GEMM A-stage)
    gemmMF<1><<<nb_gemm, 256, 0, stream>>>(H, Wt + 16384, statsP, g1, be1, T16);
    agg<<<nb_agg, 256, 0, stream>>>((const unsigned*)T16, csr2, offs, inCnt, dinv, b2, H, statsP + SREP * 256);

    // layer 3
    gemmMF<1><<<nb_gemm, 256, 0, stream>>>(H, Wt + 32768, statsP + SREP * 256, g2, be2, T16);
    agg<<<nb_agg, 256, 0, stream>>>((const unsigned*)T16, csr2, offs, inCnt, dinv, b3, H, statsP + 2 * SREP * 256);

    // pool (BN3+ReLU fused) + linear
    poolsum<<<nb_pool, 128, 0, stream>>>(H, batch, statsP + 2 * SREP * 256, g3, be3, sums);
    finalk<<<NGRAPH, 128, 0, stream>>>(sums, batch, Wl, bl, out);
}